// Round 1
// baseline (1093.891 us; speedup 1.0000x reference)
//
#include <hip/hip_runtime.h>
#include <cmath>

#define M_ROWS  65536
#define D_DIM   64
#define K_CODES 4096
#define CHUNK   128
#define TPB     128
#define NCHUNK  (K_CODES / CHUNK)

__device__ __forceinline__ float4 fma4(float4 a, float4 b, float4 c) {
  c.x = fmaf(a.x, b.x, c.x);
  c.y = fmaf(a.y, b.y, c.y);
  c.z = fmaf(a.z, b.z, c.z);
  c.w = fmaf(a.w, b.w, c.w);
  return c;
}

// ---------------------------------------------------------------------------
// e2[k] = sum(cb[k,:]^2) replicating numpy pairwise_sum for n=64:
// rounded squares, 8 strided accumulators, tree combine.
// ---------------------------------------------------------------------------
__global__ void e2_kernel(const float* __restrict__ cb, float* __restrict__ e2) {
  int k = blockIdx.x * blockDim.x + threadIdx.x;
  if (k >= K_CODES) return;
  const float* row = cb + (size_t)k * D_DIM;
  {
#pragma clang fp contract(off)
    float r0, r1, r2, r3, r4, r5, r6, r7;
    {
      float v0 = row[0], v1 = row[1], v2 = row[2], v3 = row[3];
      float v4 = row[4], v5 = row[5], v6 = row[6], v7 = row[7];
      r0 = v0 * v0; r1 = v1 * v1; r2 = v2 * v2; r3 = v3 * v3;
      r4 = v4 * v4; r5 = v5 * v5; r6 = v6 * v6; r7 = v7 * v7;
    }
#pragma unroll
    for (int i = 8; i < 64; i += 8) {
      float v0 = row[i + 0], v1 = row[i + 1], v2 = row[i + 2], v3 = row[i + 3];
      float v4 = row[i + 4], v5 = row[i + 5], v6 = row[i + 6], v7 = row[i + 7];
      r0 = r0 + v0 * v0; r1 = r1 + v1 * v1; r2 = r2 + v2 * v2; r3 = r3 + v3 * v3;
      r4 = r4 + v4 * v4; r5 = r5 + v5 * v5; r6 = r6 + v6 * v6; r7 = r7 + v7 * v7;
    }
    float s = ((r0 + r1) + (r2 + r3)) + ((r4 + r5) + (r6 + r7));
    e2[k] = s;
  }
}

// ---------------------------------------------------------------------------
// Main kernel: one thread per row. Codebook staged in LDS chunks of 128 codes.
// dist = fl(fl(z2 + e2_k) - fl(2*dot)); strict-< argmin ascending k (first min).
// ---------------------------------------------------------------------------
__global__ __launch_bounds__(TPB)
void vq_main(const float* __restrict__ z_e, const float* __restrict__ cb,
             const float* __restrict__ e2, float* __restrict__ out,
             double* __restrict__ accum) {
  __shared__ float lds_e[CHUNK * D_DIM];   // 32 KB
  __shared__ float lds_e2[CHUNK];
  __shared__ double lds_red[TPB / 64];

  const int m = blockIdx.x * TPB + threadIdx.x;

  // Load this thread's z row into registers (16 float4 = 64 VGPRs).
  float4 z4[16];
  {
    const float4* zr = (const float4*)(z_e + (size_t)m * D_DIM);
#pragma unroll
    for (int i = 0; i < 16; ++i) z4[i] = zr[i];
  }

  // z2 in numpy-pairwise pattern (scalar chain j <-> component (j&3) of even/odd quads).
  float z2;
  {
#pragma clang fp contract(off)
    float4 R0 = make_float4(0.f, 0.f, 0.f, 0.f);
    float4 R1 = make_float4(0.f, 0.f, 0.f, 0.f);
#pragma unroll
    for (int a = 0; a < 16; a += 2) {
      R0.x = R0.x + z4[a].x * z4[a].x;
      R0.y = R0.y + z4[a].y * z4[a].y;
      R0.z = R0.z + z4[a].z * z4[a].z;
      R0.w = R0.w + z4[a].w * z4[a].w;
      R1.x = R1.x + z4[a + 1].x * z4[a + 1].x;
      R1.y = R1.y + z4[a + 1].y * z4[a + 1].y;
      R1.z = R1.z + z4[a + 1].z * z4[a + 1].z;
      R1.w = R1.w + z4[a + 1].w * z4[a + 1].w;
    }
    z2 = ((R0.x + R0.y) + (R0.z + R0.w)) + ((R1.x + R1.y) + (R1.z + R1.w));
  }

  float best = INFINITY;
  int bidx = 0;

  for (int ch = 0; ch < NCHUNK; ++ch) {
    __syncthreads();
    {
      const float4* src = (const float4*)(cb + (size_t)ch * CHUNK * D_DIM);
      float4* dst = (float4*)lds_e;
#pragma unroll
      for (int i = 0; i < (CHUNK * D_DIM / 4) / TPB; ++i)  // 16 float4 per thread
        dst[threadIdx.x + i * TPB] = src[threadIdx.x + i * TPB];
      if (threadIdx.x < CHUNK)
        lds_e2[threadIdx.x] = e2[ch * CHUNK + threadIdx.x];
    }
    __syncthreads();

#pragma unroll 2
    for (int c = 0; c < CHUNK; ++c) {
      const float4* ev = (const float4*)(lds_e + c * D_DIM);  // wave-uniform -> broadcast
      float4 a0 = make_float4(0.f, 0.f, 0.f, 0.f);
      float4 a1 = make_float4(0.f, 0.f, 0.f, 0.f);
      float4 a2 = make_float4(0.f, 0.f, 0.f, 0.f);
      float4 a3 = make_float4(0.f, 0.f, 0.f, 0.f);
#pragma unroll
      for (int i = 0; i < 4; ++i) {
        a0 = fma4(z4[4 * i + 0], ev[4 * i + 0], a0);
        a1 = fma4(z4[4 * i + 1], ev[4 * i + 1], a1);
        a2 = fma4(z4[4 * i + 2], ev[4 * i + 2], a2);
        a3 = fma4(z4[4 * i + 3], ev[4 * i + 3], a3);
      }
      float dot, d;
      {
#pragma clang fp contract(off)
        float sx = (a0.x + a1.x) + (a2.x + a3.x);
        float sy = (a0.y + a1.y) + (a2.y + a3.y);
        float sz = (a0.z + a1.z) + (a2.z + a3.z);
        float sw = (a0.w + a1.w) + (a2.w + a3.w);
        dot = (sx + sy) + (sz + sw);
        float t = z2 + lds_e2[c];       // fl(z2 + e2)
        d = t - 2.0f * dot;             // fl(t - fl(2*ze)); 2*dot exact
      }
      if (d < best) { best = d; bidx = ch * CHUNK + c; }
    }
  }

  // ---- Epilogue: outputs ----
  float* out_idx  = out + (size_t)M_ROWS * D_DIM;
  float* out_scal = out_idx + M_ROWS;
  float* out_zq   = out_scal + 2;       // offset 4259842 floats (8B aligned only)

  out_idx[m] = (float)bidx;             // indices as float32

  const float4* q4 = (const float4*)(cb + (size_t)bidx * D_DIM);
  float* o0 = out + (size_t)m * D_DIM;          // z_q_st (16B aligned)
  float* o1 = out_zq + (size_t)m * D_DIM;       // z_q    (8B aligned)
  double csum = 0.0;
#pragma unroll
  for (int i = 0; i < 16; ++i) {
    float4 q = q4[i];
    ((float4*)o0)[i] = q;
    ((float2*)o1)[2 * i]     = make_float2(q.x, q.y);
    ((float2*)o1)[2 * i + 1] = make_float2(q.z, q.w);
    float dx = z4[i].x - q.x; csum += (double)dx * (double)dx;
    float dy = z4[i].y - q.y; csum += (double)dy * (double)dy;
    float dz = z4[i].z - q.z; csum += (double)dz * (double)dz;
    float dw = z4[i].w - q.w; csum += (double)dw * (double)dw;
  }

  // commit-loss reduction: wave shuffle -> LDS -> one double atomic per block
#pragma unroll
  for (int off = 32; off > 0; off >>= 1) csum += __shfl_down(csum, off);
  if ((threadIdx.x & 63) == 0) lds_red[threadIdx.x >> 6] = csum;
  __syncthreads();
  if (threadIdx.x == 0) atomicAdd(accum, lds_red[0] + lds_red[1]);
}

// ---------------------------------------------------------------------------
// Finalize: vq_loss scalar + perplexity from ema_cluster_size.
// ---------------------------------------------------------------------------
__global__ void finalize_kernel(const float* __restrict__ ema,
                                const double* __restrict__ accum,
                                float* __restrict__ out) {
  __shared__ double red[256];
  const int t = threadIdx.x;

  double s = 0.0;
  for (int i = t; i < K_CODES; i += 256) s += (double)(ema[i] + 1e-10f);
  red[t] = s;
  __syncthreads();
  for (int off = 128; off > 0; off >>= 1) {
    if (t < off) red[t] += red[t + off];
    __syncthreads();
  }
  double S = red[0];
  __syncthreads();

  double h = 0.0;
  for (int i = t; i < K_CODES; i += 256) {
    float p = (float)((ema[i] + 1e-10f) / (float)S);
    h += (double)(p * logf(p));
  }
  red[t] = h;
  __syncthreads();
  for (int off = 128; off > 0; off >>= 1) {
    if (t < off) red[t] += red[t + off];
    __syncthreads();
  }

  if (t == 0) {
    const size_t base = (size_t)M_ROWS * D_DIM + M_ROWS;
    out[base]     = 0.25f * (float)(accum[0] / (double)((size_t)M_ROWS * (size_t)D_DIM));
    out[base + 1] = expf((float)(-red[0]));
  }
}

extern "C" void kernel_launch(void* const* d_in, const int* in_sizes, int n_in,
                              void* d_out, int out_size, void* d_ws, size_t ws_size,
                              hipStream_t stream) {
  (void)in_sizes; (void)n_in; (void)out_size; (void)ws_size;
  const float* z_e = (const float*)d_in[0];
  const float* cb  = (const float*)d_in[1];
  const float* ema = (const float*)d_in[2];
  float* out = (float*)d_out;

  double* accum = (double*)d_ws;                  // 8 B used, 256 B zeroed
  float* e2     = (float*)((char*)d_ws + 256);    // K_CODES floats

  hipMemsetAsync(d_ws, 0, 256, stream);
  e2_kernel<<<K_CODES / 256, 256, 0, stream>>>(cb, e2);
  vq_main<<<M_ROWS / TPB, TPB, 0, stream>>>(z_e, cb, e2, out, accum);
  finalize_kernel<<<1, 256, 0, stream>>>(ema, accum, out);
}

// Round 2
// 293.383 us; speedup vs baseline: 3.7285x; 3.7285x over previous
//
#include <hip/hip_runtime.h>
#include <cmath>

#define M_ROWS  65536
#define D_DIM   64
#define K_CODES 4096

// d_out float offsets (outputs concatenated: z_q_st | indices | vq_loss | perplexity | z_q)
#define OFF_IDX  4194304
#define OFF_SCAL 4259840
#define OFF_ZQ   4259842

// scratch byte offsets inside d_out (overwritten by gather_kernel at the end)
#define IMG_OFF  (4u << 20)
#define CAND_OFF (8u << 20)

// codebook chunk image layout (bf16 hi/lo split, padded rows to kill LDS bank conflicts)
#define CHUNK    128
#define NCH      32
#define ROWB     144            // 72 shorts per row (64 data + 8 pad) -> 2-way-max bank aliasing
#define CH_LO    18432          // 128*144
#define CH_E2    36864
#define CH_BYTES 37376
#define CH_QUADS 2336           // CH_BYTES/16

typedef __attribute__((ext_vector_type(8))) short s16x8;
typedef __attribute__((ext_vector_type(4))) float f32x4;

__device__ __forceinline__ unsigned short f2bf(float f) {   // RNE float->bf16 bits
  unsigned int u = __float_as_uint(f);
  return (unsigned short)((u + 0x7FFFu + ((u >> 16) & 1u)) >> 16);
}
__device__ __forceinline__ float bf2f(unsigned short h) {
  return __uint_as_float(((unsigned int)h) << 16);
}

// ---------------------------------------------------------------------------
// K1: e2[k] (numpy-pairwise exact) + bf16 hi/lo split image + e2+32 bias array
// ---------------------------------------------------------------------------
__global__ void split_cb_kernel(const float* __restrict__ cb,
                                float* __restrict__ e2,
                                char* __restrict__ img) {
  int k = blockIdx.x * 256 + threadIdx.x;
  if (k >= K_CODES) return;
  const float* row = cb + (size_t)k * D_DIM;
  float s;
  {
#pragma clang fp contract(off)
    float r0, r1, r2, r3, r4, r5, r6, r7;
    {
      float v0 = row[0], v1 = row[1], v2 = row[2], v3 = row[3];
      float v4 = row[4], v5 = row[5], v6 = row[6], v7 = row[7];
      r0 = v0 * v0; r1 = v1 * v1; r2 = v2 * v2; r3 = v3 * v3;
      r4 = v4 * v4; r5 = v5 * v5; r6 = v6 * v6; r7 = v7 * v7;
    }
#pragma unroll
    for (int i = 8; i < 64; i += 8) {
      float v0 = row[i + 0], v1 = row[i + 1], v2 = row[i + 2], v3 = row[i + 3];
      float v4 = row[i + 4], v5 = row[i + 5], v6 = row[i + 6], v7 = row[i + 7];
      r0 = r0 + v0 * v0; r1 = r1 + v1 * v1; r2 = r2 + v2 * v2; r3 = r3 + v3 * v3;
      r4 = r4 + v4 * v4; r5 = r5 + v5 * v5; r6 = r6 + v6 * v6; r7 = r7 + v7 * v7;
    }
    s = ((r0 + r1) + (r2 + r3)) + ((r4 + r5) + (r6 + r7));
  }
  e2[k] = s;

  int c = k >> 7, r = k & 127;
  char* base = img + (size_t)c * CH_BYTES;
  unsigned short* hi = (unsigned short*)(base + r * ROWB);
  unsigned short* lo = (unsigned short*)(base + CH_LO + r * ROWB);
#pragma unroll
  for (int d = 0; d < 64; ++d) {
    float f = row[d];
    unsigned short h = f2bf(f);
    hi[d] = h;
    lo[d] = f2bf(f - bf2f(h));
  }
#pragma unroll
  for (int d = 64; d < 72; ++d) { hi[d] = 0; lo[d] = 0; }
  ((float*)(base + CH_E2))[r] = s + 32.0f;   // bias keeps key values positive
}

// ---------------------------------------------------------------------------
// K2: MFMA distance pass. val = (e2+32) - 2*z.e  via 3 bf16-split products.
// Sortable key = (bits & ~0xFF) | global_ktile; per-element top-2 (min/max/min);
// per-row top-4-of-32 written to cands.
// ---------------------------------------------------------------------------
__global__ __launch_bounds__(256)
void vq_mfma_kernel(const float* __restrict__ z_e,
                    const char* __restrict__ img,
                    unsigned int* __restrict__ cands) {
  __shared__ union {
    char raw[CH_BYTES];
    uint4 q[CH_QUADS];
    unsigned int cand[CH_BYTES / 4];
  } sm;
  const int tid  = threadIdx.x;
  const int wave = tid >> 6, lane = tid & 63;
  const int quad = lane >> 4, c16 = lane & 15;
  const int mb   = blockIdx.x * 128 + wave * 32;

  // A-fragments: z rows scaled by -2, split into bf16 hi/lo.
  // Layout: A[m=lane&15][k = quad*8 + j] per 16x16x32 step (d = 32*s + quad*8 + j).
  s16x8 zh[2][2], zl[2][2];
#pragma unroll
  for (int mt = 0; mt < 2; ++mt) {
    int m = mb + mt * 16 + c16;
#pragma unroll
    for (int s = 0; s < 2; ++s) {
      const float* zp = z_e + (size_t)m * 64 + s * 32 + quad * 8;
      float4 fa = ((const float4*)zp)[0];
      float4 fb = ((const float4*)zp)[1];
      float v[8] = {fa.x, fa.y, fa.z, fa.w, fb.x, fb.y, fb.z, fb.w};
      union { s16x8 v8; unsigned short e[8]; } H, L;
#pragma unroll
      for (int j = 0; j < 8; ++j) {
        float f = -2.0f * v[j];
        unsigned short h = f2bf(f);
        H.e[j] = h;
        L.e[j] = f2bf(f - bf2f(h));
      }
      zh[mt][s] = H.v8;
      zl[mt][s] = L.v8;
    }
  }

  unsigned int b1[2][4], b2[2][4];
#pragma unroll
  for (int mt = 0; mt < 2; ++mt)
#pragma unroll
    for (int r = 0; r < 4; ++r) { b1[mt][r] = 0xFFFFFFFFu; b2[mt][r] = 0xFFFFFFFFu; }

  for (int c = 0; c < NCH; ++c) {
    __syncthreads();
    const uint4* src = (const uint4*)(img + (size_t)c * CH_BYTES);
    for (int i = tid; i < CH_QUADS; i += 256) sm.q[i] = src[i];
    __syncthreads();

#pragma unroll 1
    for (int t = 0; t < 8; ++t) {
      const char* hrow = sm.raw + (t * 16 + c16) * ROWB;   // code n = c16 (+tile base)
      s16x8 Bh0 = *(const s16x8*)(hrow + quad * 16);
      s16x8 Bh1 = *(const s16x8*)(hrow + 64 + quad * 16);
      s16x8 Bl0 = *(const s16x8*)(hrow + CH_LO + quad * 16);
      s16x8 Bl1 = *(const s16x8*)(hrow + CH_LO + 64 + quad * 16);
      float e2v = *(const float*)(sm.raw + CH_E2 + (t * 16 + c16) * 4);
      unsigned int tid8 = (unsigned int)(c * 8 + t);       // global k-tile id, 8 bits

#pragma unroll
      for (int mt = 0; mt < 2; ++mt) {
        f32x4 acc = {0.f, 0.f, 0.f, 0.f};
        acc = __builtin_amdgcn_mfma_f32_16x16x32_bf16(zh[mt][0], Bh0, acc, 0, 0, 0);
        acc = __builtin_amdgcn_mfma_f32_16x16x32_bf16(zh[mt][1], Bh1, acc, 0, 0, 0);
        acc = __builtin_amdgcn_mfma_f32_16x16x32_bf16(zl[mt][0], Bh0, acc, 0, 0, 0);
        acc = __builtin_amdgcn_mfma_f32_16x16x32_bf16(zl[mt][1], Bh1, acc, 0, 0, 0);
        acc = __builtin_amdgcn_mfma_f32_16x16x32_bf16(zh[mt][0], Bl0, acc, 0, 0, 0);
        acc = __builtin_amdgcn_mfma_f32_16x16x32_bf16(zh[mt][1], Bl1, acc, 0, 0, 0);
#pragma unroll
        for (int r = 0; r < 4; ++r) {
          float v = acc[r] + e2v;
          unsigned int key = (__float_as_uint(v) & 0xFFFFFF00u) | tid8;
          unsigned int nb1 = min(b1[mt][r], key);
          b2[mt][r] = min(b2[mt][r], max(b1[mt][r], key));
          b1[mt][r] = nb1;
        }
      }
    }
  }

  __syncthreads();   // done reading sm.raw -> reuse as candidate buffer
#pragma unroll
  for (int mt = 0; mt < 2; ++mt)
#pragma unroll
    for (int r = 0; r < 4; ++r) {
      int row = (wave * 2 + mt) * 16 + quad * 4 + r;       // C: col=lane&15, row=quad*4+reg
      sm.cand[row * 32 + c16 * 2 + 0] = b1[mt][r];
      sm.cand[row * 32 + c16 * 2 + 1] = b2[mt][r];
    }
  __syncthreads();

  if (tid < 128) {
    unsigned int kk[4] = {0xFFFFFFFFu, 0xFFFFFFFFu, 0xFFFFFFFFu, 0xFFFFFFFFu};
    unsigned int vv[4] = {0, 0, 0, 0};
    for (int j = 0; j < 32; ++j) {
      unsigned int key = sm.cand[tid * 32 + j];
      if (key < kk[3]) {
        kk[3] = key;
        vv[3] = (key & 0xFFu) * 16 + (unsigned int)(j >> 1);  // k = tile*16 + col
        for (int p = 3; p > 0; --p)
          if (kk[p] < kk[p - 1]) {
            unsigned int a = kk[p]; kk[p] = kk[p - 1]; kk[p - 1] = a;
            unsigned int b = vv[p]; vv[p] = vv[p - 1]; vv[p - 1] = b;
          }
      }
    }
    int grow = blockIdx.x * 128 + tid;
#pragma unroll
    for (int i = 0; i < 4; ++i) cands[grow * 4 + i] = vv[i];
  }
}

// ---------------------------------------------------------------------------
// K3: exact re-check of <=4 candidates per row with the numpy-matched formula
// (verified bit-compatible in round 1), first-min tie-break; writes indices
// (as float) and accumulates commit loss.
// ---------------------------------------------------------------------------
__global__ __launch_bounds__(256)
void exact_pick_kernel(const float* __restrict__ z_e, const float* __restrict__ cb,
                       const float* __restrict__ e2, const unsigned int* __restrict__ cands,
                       float* __restrict__ out, double* __restrict__ accum) {
  __shared__ double lds_red[4];
  const int m = blockIdx.x * 256 + threadIdx.x;

  float4 z4[16];
  const float4* zr = (const float4*)(z_e + (size_t)m * 64);
#pragma unroll
  for (int i = 0; i < 16; ++i) z4[i] = zr[i];

  float z2;
  {
#pragma clang fp contract(off)
    float4 R0 = make_float4(0.f, 0.f, 0.f, 0.f);
    float4 R1 = make_float4(0.f, 0.f, 0.f, 0.f);
#pragma unroll
    for (int a = 0; a < 16; a += 2) {
      R0.x = R0.x + z4[a].x * z4[a].x;
      R0.y = R0.y + z4[a].y * z4[a].y;
      R0.z = R0.z + z4[a].z * z4[a].z;
      R0.w = R0.w + z4[a].w * z4[a].w;
      R1.x = R1.x + z4[a + 1].x * z4[a + 1].x;
      R1.y = R1.y + z4[a + 1].y * z4[a + 1].y;
      R1.z = R1.z + z4[a + 1].z * z4[a + 1].z;
      R1.w = R1.w + z4[a + 1].w * z4[a + 1].w;
    }
    z2 = ((R0.x + R0.y) + (R0.z + R0.w)) + ((R1.x + R1.y) + (R1.z + R1.w));
  }

  float bd = INFINITY;
  int bk = K_CODES;
#pragma unroll 1
  for (int i = 0; i < 4; ++i) {
    int k = (int)cands[(size_t)m * 4 + i];
    const float4* ev = (const float4*)(cb + (size_t)k * 64);
    float4 a0 = make_float4(0.f, 0.f, 0.f, 0.f);
    float4 a1 = make_float4(0.f, 0.f, 0.f, 0.f);
    float4 a2 = make_float4(0.f, 0.f, 0.f, 0.f);
    float4 a3 = make_float4(0.f, 0.f, 0.f, 0.f);
#pragma unroll
    for (int j = 0; j < 4; ++j) {
      float4 e0 = ev[4 * j + 0], e1 = ev[4 * j + 1], e2v = ev[4 * j + 2], e3 = ev[4 * j + 3];
      a0.x = fmaf(z4[4 * j + 0].x, e0.x, a0.x); a0.y = fmaf(z4[4 * j + 0].y, e0.y, a0.y);
      a0.z = fmaf(z4[4 * j + 0].z, e0.z, a0.z); a0.w = fmaf(z4[4 * j + 0].w, e0.w, a0.w);
      a1.x = fmaf(z4[4 * j + 1].x, e1.x, a1.x); a1.y = fmaf(z4[4 * j + 1].y, e1.y, a1.y);
      a1.z = fmaf(z4[4 * j + 1].z, e1.z, a1.z); a1.w = fmaf(z4[4 * j + 1].w, e1.w, a1.w);
      a2.x = fmaf(z4[4 * j + 2].x, e2v.x, a2.x); a2.y = fmaf(z4[4 * j + 2].y, e2v.y, a2.y);
      a2.z = fmaf(z4[4 * j + 2].z, e2v.z, a2.z); a2.w = fmaf(z4[4 * j + 2].w, e2v.w, a2.w);
      a3.x = fmaf(z4[4 * j + 3].x, e3.x, a3.x); a3.y = fmaf(z4[4 * j + 3].y, e3.y, a3.y);
      a3.z = fmaf(z4[4 * j + 3].z, e3.z, a3.z); a3.w = fmaf(z4[4 * j + 3].w, e3.w, a3.w);
    }
    float d;
    {
#pragma clang fp contract(off)
      float sx = (a0.x + a1.x) + (a2.x + a3.x);
      float sy = (a0.y + a1.y) + (a2.y + a3.y);
      float sz = (a0.z + a1.z) + (a2.z + a3.z);
      float sw = (a0.w + a1.w) + (a2.w + a3.w);
      float dot = (sx + sy) + (sz + sw);
      float tt = z2 + e2[k];
      d = tt - 2.0f * dot;
    }
    if (d < bd || (d == bd && k < bk)) { bd = d; bk = k; }
  }

  out[OFF_IDX + m] = (float)bk;

  const float* q = cb + (size_t)bk * 64;
  const float* zs = (const float*)z4;
  double csum = 0.0;
#pragma unroll
  for (int i = 0; i < 64; ++i) {
    float dx = zs[i] - q[i];
    csum += (double)dx * (double)dx;
  }
#pragma unroll
  for (int off = 32; off > 0; off >>= 1) csum += __shfl_down(csum, off);
  if ((threadIdx.x & 63) == 0) lds_red[threadIdx.x >> 6] = csum;
  __syncthreads();
  if (threadIdx.x == 0)
    atomicAdd(accum, (lds_red[0] + lds_red[1]) + (lds_red[2] + lds_red[3]));
}

// ---------------------------------------------------------------------------
// K4: gather z_q_st and z_q from the codebook (overwrites d_out scratch regions)
// ---------------------------------------------------------------------------
__global__ void gather_kernel(const float* __restrict__ cb, float* __restrict__ out) {
  int t = blockIdx.x * 256 + threadIdx.x;
  int m = t >> 2, qd = t & 3;
  int k = (int)out[OFF_IDX + m];
  const float4* q = (const float4*)(cb + (size_t)k * 64 + qd * 16);
  float4* o0 = (float4*)(out + (size_t)m * 64 + qd * 16);
  float* o1 = out + OFF_ZQ + (size_t)m * 64 + qd * 16;   // 8B-aligned only
#pragma unroll
  for (int i = 0; i < 4; ++i) {
    float4 v = q[i];
    o0[i] = v;
    ((float2*)o1)[2 * i]     = make_float2(v.x, v.y);
    ((float2*)o1)[2 * i + 1] = make_float2(v.z, v.w);
  }
}

// ---------------------------------------------------------------------------
// K5: vq_loss + perplexity
// ---------------------------------------------------------------------------
__global__ void finalize_kernel(const float* __restrict__ ema,
                                const double* __restrict__ accum,
                                float* __restrict__ out) {
  __shared__ double red[256];
  const int t = threadIdx.x;

  double s = 0.0;
  for (int i = t; i < K_CODES; i += 256) s += (double)(ema[i] + 1e-10f);
  red[t] = s;
  __syncthreads();
  for (int off = 128; off > 0; off >>= 1) {
    if (t < off) red[t] += red[t + off];
    __syncthreads();
  }
  double S = red[0];
  __syncthreads();

  double h = 0.0;
  for (int i = t; i < K_CODES; i += 256) {
    float p = (float)((ema[i] + 1e-10f) / (float)S);
    h += (double)(p * logf(p));
  }
  red[t] = h;
  __syncthreads();
  for (int off = 128; off > 0; off >>= 1) {
    if (t < off) red[t] += red[t + off];
    __syncthreads();
  }

  if (t == 0) {
    out[OFF_SCAL]     = 0.25f * (float)(accum[0] / (double)((size_t)M_ROWS * (size_t)D_DIM));
    out[OFF_SCAL + 1] = expf((float)(-red[0]));
  }
}

extern "C" void kernel_launch(void* const* d_in, const int* in_sizes, int n_in,
                              void* d_out, int out_size, void* d_ws, size_t ws_size,
                              hipStream_t stream) {
  (void)in_sizes; (void)n_in; (void)out_size; (void)ws_size;
  const float* z_e = (const float*)d_in[0];
  const float* cb  = (const float*)d_in[1];
  const float* ema = (const float*)d_in[2];
  float* out = (float*)d_out;

  double* accum = (double*)d_ws;                          // 8 B used, 256 B zeroed
  float* e2     = (float*)((char*)d_ws + 256);            // K_CODES floats
  char* img            = (char*)d_out + IMG_OFF;          // 1.17 MB scratch in d_out
  unsigned int* cands  = (unsigned int*)((char*)d_out + CAND_OFF);  // 1 MB scratch

  hipMemsetAsync(d_ws, 0, 256, stream);
  split_cb_kernel<<<K_CODES / 256, 256, 0, stream>>>(cb, e2, img);
  vq_mfma_kernel<<<M_ROWS / 128, 256, 0, stream>>>(z_e, img, cands);
  exact_pick_kernel<<<M_ROWS / 256, 256, 0, stream>>>(z_e, cb, e2, cands, out, accum);
  gather_kernel<<<M_ROWS * 4 / 256, 256, 0, stream>>>(cb, out);
  finalize_kernel<<<1, 256, 0, stream>>>(ema, accum, out);
}

// Round 4
// 274.837 us; speedup vs baseline: 3.9802x; 1.0675x over previous
//
#include <hip/hip_runtime.h>
#include <cmath>

#define M_ROWS  65536
#define D_DIM   64
#define K_CODES 4096

// d_out float offsets (z_q_st | indices | vq_loss | perplexity | z_q)
#define OFF_IDX  4194304
#define OFF_SCAL 4259840
#define OFF_ZQ   4259842

// scratch regions inside d_out
#define IMG_OFF   (4u << 20)                 // codebook image, 1.18 MB (inside z_q_st region, used before it's written)
#define E2B_OFF   (IMG_OFF + 1179648u)       // e2+32 array, 16 KB
#define CANDB_OFF 17039368u                  // == OFF_ZQ*4 : candidate lists, 4 MB (overwritten by final z_q memcpy)

// codebook chunk image: 128 codes, bf16 hi/lo split, row stride 144 B (bank skew)
#define ROWB     144
#define CH_LO    18432                        // 128*144
#define CH_BYTES 36864                        // hi + lo
#define CH_QUADS 2304                         // CH_BYTES/16, == 9*256
#define NSPLIT   4
#define NCHB     8                            // chunks per block (1024 codes)

typedef __attribute__((ext_vector_type(8))) short s16x8;
typedef __attribute__((ext_vector_type(4))) float f32x4;

__device__ __forceinline__ unsigned short f2bf(float f) {   // RNE float->bf16 bits
  unsigned int u = __float_as_uint(f);
  return (unsigned short)((u + 0x7FFFu + ((u >> 16) & 1u)) >> 16);
}
__device__ __forceinline__ float bf2f(unsigned short h) {
  return __uint_as_float(((unsigned int)h) << 16);
}

// ---------------------------------------------------------------------------
// K1: e2[k] (numpy-pairwise exact) + bf16 hi/lo split image + (e2+32) array
// ---------------------------------------------------------------------------
__global__ void split_cb_kernel(const float* __restrict__ cb,
                                float* __restrict__ e2,
                                char* __restrict__ img,
                                float* __restrict__ e2b) {
  int k = blockIdx.x * 256 + threadIdx.x;
  if (k >= K_CODES) return;
  const float* row = cb + (size_t)k * D_DIM;
  float s;
  {
#pragma clang fp contract(off)
    float r0, r1, r2, r3, r4, r5, r6, r7;
    {
      float v0 = row[0], v1 = row[1], v2 = row[2], v3 = row[3];
      float v4 = row[4], v5 = row[5], v6 = row[6], v7 = row[7];
      r0 = v0 * v0; r1 = v1 * v1; r2 = v2 * v2; r3 = v3 * v3;
      r4 = v4 * v4; r5 = v5 * v5; r6 = v6 * v6; r7 = v7 * v7;
    }
#pragma unroll
    for (int i = 8; i < 64; i += 8) {
      float v0 = row[i + 0], v1 = row[i + 1], v2 = row[i + 2], v3 = row[i + 3];
      float v4 = row[i + 4], v5 = row[i + 5], v6 = row[i + 6], v7 = row[i + 7];
      r0 = r0 + v0 * v0; r1 = r1 + v1 * v1; r2 = r2 + v2 * v2; r3 = r3 + v3 * v3;
      r4 = r4 + v4 * v4; r5 = r5 + v5 * v5; r6 = r6 + v6 * v6; r7 = r7 + v7 * v7;
    }
    s = ((r0 + r1) + (r2 + r3)) + ((r4 + r5) + (r6 + r7));
  }
  e2[k] = s;
  e2b[k] = s + 32.0f;                         // bias keeps key values positive

  int c = k >> 7, r = k & 127;
  char* base = img + (size_t)c * CH_BYTES;
  unsigned short* hi = (unsigned short*)(base + r * ROWB);
  unsigned short* lo = (unsigned short*)(base + CH_LO + r * ROWB);
#pragma unroll
  for (int d = 0; d < 64; ++d) {
    float f = row[d];
    unsigned short h = f2bf(f);
    hi[d] = h;
    lo[d] = f2bf(f - bf2f(h));
  }
#pragma unroll
  for (int d = 64; d < 72; ++d) { hi[d] = 0; lo[d] = 0; }
}

// ---------------------------------------------------------------------------
// K2: MFMA distance pass, K-split by 4. Each wave = 64 rows (mt=4); each block
// = 256 rows x 1024 codes. val = (e2+32) - 2 z.e via 3 bf16-split products,
// e2 folded into MFMA C-input. Sortable key = (bits & ~0xFF)|tile; per-element
// top-2 via min/max/min; per-row top-4-of-32 -> cands[row*16 + split*4 + i].
// ---------------------------------------------------------------------------
__global__ __launch_bounds__(256, 4)
void vq_mfma_kernel(const float* __restrict__ z_e,
                    const char* __restrict__ img,
                    const float* __restrict__ e2b,
                    unsigned int* __restrict__ cands) {
  __shared__ union {
    char raw[CH_BYTES];
    uint4 q[CH_QUADS];
    unsigned int cand[256 * 32];
  } sm;
  const int tid  = threadIdx.x;
  const int wave = tid >> 6, lane = tid & 63;
  const int quad = lane >> 4, c16 = lane & 15;
  const int rb   = blockIdx.x >> 2;           // row-group of 256
  const int sp   = blockIdx.x & 3;            // K-split id
  const int mb   = rb * 256 + wave * 64;

  // A-fragments: 4 row-tiles x (k-halves) x (hi/lo), A[m=lane&15][k=quad*8+j]
  s16x8 zh[4][2], zl[4][2];
#pragma unroll
  for (int mt = 0; mt < 4; ++mt) {
    int m = mb + mt * 16 + c16;
#pragma unroll
    for (int s = 0; s < 2; ++s) {
      const float* zp = z_e + (size_t)m * 64 + s * 32 + quad * 8;
      float4 fa = ((const float4*)zp)[0];
      float4 fb = ((const float4*)zp)[1];
      float v[8] = {fa.x, fa.y, fa.z, fa.w, fb.x, fb.y, fb.z, fb.w};
      union { s16x8 v8; unsigned short e[8]; } H, L;
#pragma unroll
      for (int j = 0; j < 8; ++j) {
        float f = -2.0f * v[j];
        unsigned short h = f2bf(f);
        H.e[j] = h;
        L.e[j] = f2bf(f - bf2f(h));
      }
      zh[mt][s] = H.v8;
      zl[mt][s] = L.v8;
    }
  }

  unsigned int b1[4][4], b2[4][4];
#pragma unroll
  for (int mt = 0; mt < 4; ++mt)
#pragma unroll
    for (int r = 0; r < 4; ++r) { b1[mt][r] = 0xFFFFFFFFu; b2[mt][r] = 0xFFFFFFFFu; }

  for (int c = 0; c < NCHB; ++c) {
    __syncthreads();
    {
      const uint4* src = (const uint4*)(img + (size_t)(sp * NCHB + c) * CH_BYTES);
#pragma unroll
      for (int i = 0; i < 9; ++i) sm.q[tid + i * 256] = src[tid + i * 256];
    }
    __syncthreads();

#pragma unroll 1
    for (int t = 0; t < 8; ++t) {
      float e2v = e2b[sp * 1024 + c * 128 + t * 16 + c16];
      const char* hrow = sm.raw + (t * 16 + c16) * ROWB;
      s16x8 Bh0 = *(const s16x8*)(hrow + quad * 16);
      s16x8 Bh1 = *(const s16x8*)(hrow + 64 + quad * 16);
      s16x8 Bl0 = *(const s16x8*)(hrow + CH_LO + quad * 16);
      s16x8 Bl1 = *(const s16x8*)(hrow + CH_LO + 64 + quad * 16);
      unsigned int tid8 = (unsigned int)(sp * 64 + c * 8 + t);  // global 16-code tile id

#pragma unroll
      for (int mt = 0; mt < 4; ++mt) {
        f32x4 acc = {e2v, e2v, e2v, e2v};     // e2 is col-constant -> C-input
        acc = __builtin_amdgcn_mfma_f32_16x16x32_bf16(zh[mt][0], Bh0, acc, 0, 0, 0);
        acc = __builtin_amdgcn_mfma_f32_16x16x32_bf16(zh[mt][1], Bh1, acc, 0, 0, 0);
        acc = __builtin_amdgcn_mfma_f32_16x16x32_bf16(zl[mt][0], Bh0, acc, 0, 0, 0);
        acc = __builtin_amdgcn_mfma_f32_16x16x32_bf16(zl[mt][1], Bh1, acc, 0, 0, 0);
        acc = __builtin_amdgcn_mfma_f32_16x16x32_bf16(zh[mt][0], Bl0, acc, 0, 0, 0);
        acc = __builtin_amdgcn_mfma_f32_16x16x32_bf16(zh[mt][1], Bl1, acc, 0, 0, 0);
#pragma unroll
        for (int r = 0; r < 4; ++r) {
          unsigned int key = (__float_as_uint(acc[r]) & 0xFFFFFF00u) | tid8;
          unsigned int nb1 = min(b1[mt][r], key);
          b2[mt][r] = min(b2[mt][r], max(b1[mt][r], key));
          b1[mt][r] = nb1;
        }
      }
    }
  }

  __syncthreads();   // reuse sm as candidate buffer
#pragma unroll
  for (int mt = 0; mt < 4; ++mt)
#pragma unroll
    for (int r = 0; r < 4; ++r) {
      int row = wave * 64 + mt * 16 + quad * 4 + r;   // C: col=lane&15, row=quad*4+reg
      sm.cand[row * 32 + c16 * 2 + 0] = b1[mt][r];
      sm.cand[row * 32 + c16 * 2 + 1] = b2[mt][r];
    }
  __syncthreads();

  {
    unsigned int kk[4] = {0xFFFFFFFFu, 0xFFFFFFFFu, 0xFFFFFFFFu, 0xFFFFFFFFu};
    unsigned int vv[4] = {0, 0, 0, 0};
    for (int j = 0; j < 32; ++j) {
      unsigned int key = sm.cand[tid * 32 + j];
      if (key < kk[3]) {
        kk[3] = key;
        vv[3] = (key & 0xFFu) * 16 + (unsigned int)(j >> 1);  // k = tile*16 + col
        for (int p = 3; p > 0; --p)
          if (kk[p] < kk[p - 1]) {
            unsigned int a = kk[p]; kk[p] = kk[p - 1]; kk[p - 1] = a;
            unsigned int b = vv[p]; vv[p] = vv[p - 1]; vv[p - 1] = b;
          }
      }
    }
    int grow = rb * 256 + tid;
#pragma unroll
    for (int i = 0; i < 4; ++i) cands[grow * 16 + sp * 4 + i] = vv[i];
  }
}

// ---------------------------------------------------------------------------
// K3: exact re-check of 16 candidates/row, 16 lanes per row (one cand each),
// numpy-exact formula, first-min tie-break. Writes idx + z_q_st + loss accum.
// ---------------------------------------------------------------------------
__global__ __launch_bounds__(256)
void exact_pick_kernel(const float* __restrict__ z_e, const float* __restrict__ cb,
                       const float* __restrict__ e2, const unsigned int* __restrict__ cands,
                       float* __restrict__ out, double* __restrict__ accum) {
  __shared__ double lds_red[4];
  const int tid = threadIdx.x;
  const int r   = blockIdx.x * 16 + (tid >> 4);   // row
  const int j   = tid & 15;                       // candidate slot / element group

  float4 z4[16];
  const float4* zr = (const float4*)(z_e + (size_t)r * 64);
#pragma unroll
  for (int i = 0; i < 16; ++i) z4[i] = zr[i];

  float z2;
  {
#pragma clang fp contract(off)
    float4 R0 = make_float4(0.f, 0.f, 0.f, 0.f);
    float4 R1 = make_float4(0.f, 0.f, 0.f, 0.f);
#pragma unroll
    for (int a = 0; a < 16; a += 2) {
      R0.x = R0.x + z4[a].x * z4[a].x;
      R0.y = R0.y + z4[a].y * z4[a].y;
      R0.z = R0.z + z4[a].z * z4[a].z;
      R0.w = R0.w + z4[a].w * z4[a].w;
      R1.x = R1.x + z4[a + 1].x * z4[a + 1].x;
      R1.y = R1.y + z4[a + 1].y * z4[a + 1].y;
      R1.z = R1.z + z4[a + 1].z * z4[a + 1].z;
      R1.w = R1.w + z4[a + 1].w * z4[a + 1].w;
    }
    z2 = ((R0.x + R0.y) + (R0.z + R0.w)) + ((R1.x + R1.y) + (R1.z + R1.w));
  }

  // each lane: exact distance of its candidate
  int k = (int)cands[(size_t)r * 16 + j];
  float d;
  {
    const float4* ev = (const float4*)(cb + (size_t)k * 64);
    float4 a0 = make_float4(0.f, 0.f, 0.f, 0.f);
    float4 a1 = make_float4(0.f, 0.f, 0.f, 0.f);
    float4 a2 = make_float4(0.f, 0.f, 0.f, 0.f);
    float4 a3 = make_float4(0.f, 0.f, 0.f, 0.f);
#pragma unroll
    for (int q = 0; q < 4; ++q) {
      float4 e0 = ev[4 * q + 0], e1 = ev[4 * q + 1], e2v = ev[4 * q + 2], e3 = ev[4 * q + 3];
      a0.x = fmaf(z4[4 * q + 0].x, e0.x, a0.x); a0.y = fmaf(z4[4 * q + 0].y, e0.y, a0.y);
      a0.z = fmaf(z4[4 * q + 0].z, e0.z, a0.z); a0.w = fmaf(z4[4 * q + 0].w, e0.w, a0.w);
      a1.x = fmaf(z4[4 * q + 1].x, e1.x, a1.x); a1.y = fmaf(z4[4 * q + 1].y, e1.y, a1.y);
      a1.z = fmaf(z4[4 * q + 1].z, e1.z, a1.z); a1.w = fmaf(z4[4 * q + 1].w, e1.w, a1.w);
      a2.x = fmaf(z4[4 * q + 2].x, e2v.x, a2.x); a2.y = fmaf(z4[4 * q + 2].y, e2v.y, a2.y);
      a2.z = fmaf(z4[4 * q + 2].z, e2v.z, a2.z); a2.w = fmaf(z4[4 * q + 2].w, e2v.w, a2.w);
      a3.x = fmaf(z4[4 * q + 3].x, e3.x, a3.x); a3.y = fmaf(z4[4 * q + 3].y, e3.y, a3.y);
      a3.z = fmaf(z4[4 * q + 3].z, e3.z, a3.z); a3.w = fmaf(z4[4 * q + 3].w, e3.w, a3.w);
    }
    {
#pragma clang fp contract(off)
      float sx = (a0.x + a1.x) + (a2.x + a3.x);
      float sy = (a0.y + a1.y) + (a2.y + a3.y);
      float sz = (a0.z + a1.z) + (a2.z + a3.z);
      float sw = (a0.w + a1.w) + (a2.w + a3.w);
      float dot = (sx + sy) + (sz + sw);
      float tt = z2 + e2[k];
      d = tt - 2.0f * dot;
    }
  }

  // min over 16 lanes, tie -> smaller k (numpy first-occurrence)
#pragma unroll
  for (int off = 8; off > 0; off >>= 1) {
    float d2 = __shfl_down(d, off, 16);
    int   k2 = __shfl_down(k, off, 16);
    if (d2 < d || (d2 == d && k2 < k)) { d = d2; k = k2; }
  }
  int bk = __shfl(k, 0, 16);

  if (j == 0) out[OFF_IDX + r] = (float)bk;

  // lane j writes elements 4j..4j+3 of z_q_st; partial commit loss
  float4 q = ((const float4*)(cb + (size_t)bk * 64))[j];
  float4 zv = ((const float4*)(z_e + (size_t)r * 64))[j];
  ((float4*)(out + (size_t)r * 64))[j] = q;
  double csum;
  {
    float dx = zv.x - q.x, dy = zv.y - q.y, dz = zv.z - q.z, dw = zv.w - q.w;
    csum = (double)dx * dx + (double)dy * dy + (double)dz * dz + (double)dw * dw;
  }
#pragma unroll
  for (int off = 32; off > 0; off >>= 1) csum += __shfl_down(csum, off);
  if ((tid & 63) == 0) lds_red[tid >> 6] = csum;
  __syncthreads();
  if (tid == 0)
    atomicAdd(accum, (lds_red[0] + lds_red[1]) + (lds_red[2] + lds_red[3]));
}

// ---------------------------------------------------------------------------
// K4: vq_loss + perplexity
// ---------------------------------------------------------------------------
__global__ void finalize_kernel(const float* __restrict__ ema,
                                const double* __restrict__ accum,
                                float* __restrict__ out) {
  __shared__ double red[256];
  const int t = threadIdx.x;

  double s = 0.0;
  for (int i = t; i < K_CODES; i += 256) s += (double)(ema[i] + 1e-10f);
  red[t] = s;
  __syncthreads();
  for (int off = 128; off > 0; off >>= 1) {
    if (t < off) red[t] += red[t + off];
    __syncthreads();
  }
  double S = red[0];
  __syncthreads();

  double h = 0.0;
  for (int i = t; i < K_CODES; i += 256) {
    float p = (float)((ema[i] + 1e-10f) / (float)S);
    h += (double)(p * logf(p));
  }
  red[t] = h;
  __syncthreads();
  for (int off = 128; off > 0; off >>= 1) {
    if (t < off) red[t] += red[t + off];
    __syncthreads();
  }

  if (t == 0) {
    out[OFF_SCAL]     = 0.25f * (float)(accum[0] / (double)((size_t)M_ROWS * (size_t)D_DIM));
    out[OFF_SCAL + 1] = expf((float)(-red[0]));
  }
}

extern "C" void kernel_launch(void* const* d_in, const int* in_sizes, int n_in,
                              void* d_out, int out_size, void* d_ws, size_t ws_size,
                              hipStream_t stream) {
  (void)in_sizes; (void)n_in; (void)out_size; (void)ws_size;
  const float* z_e = (const float*)d_in[0];
  const float* cb  = (const float*)d_in[1];
  const float* ema = (const float*)d_in[2];
  float* out = (float*)d_out;

  double* accum = (double*)d_ws;                            // 8 B used, 256 B zeroed
  float* e2     = (float*)((char*)d_ws + 256);              // K_CODES floats
  char*  img    = (char*)d_out + IMG_OFF;                   // 1.18 MB scratch
  float* e2b    = (float*)((char*)d_out + E2B_OFF);         // 16 KB scratch
  unsigned int* cands = (unsigned int*)((char*)d_out + CANDB_OFF);  // 4 MB scratch in z_q region

  (void)hipMemsetAsync(d_ws, 0, 256, stream);
  split_cb_kernel<<<K_CODES / 256, 256, 0, stream>>>(cb, e2, img, e2b);
  vq_mfma_kernel<<<(M_ROWS / 256) * NSPLIT, 256, 0, stream>>>(z_e, img, e2b, cands);
  exact_pick_kernel<<<M_ROWS * 16 / 256, 256, 0, stream>>>(z_e, cb, e2, cands, out, accum);
  // z_q == z_q_st numerically: d2d copy (also overwrites the cand scratch)
  (void)hipMemcpyAsync(out + OFF_ZQ, out, (size_t)M_ROWS * D_DIM * sizeof(float),
                       hipMemcpyDeviceToDevice, stream);
  finalize_kernel<<<1, 256, 0, stream>>>(ema, accum, out);
}